// Round 2
// baseline (768.121 us; speedup 1.0000x reference)
//
#include <hip/hip_runtime.h>

// All float tensors are float32 per the reference; rows/cols are int32.
// Output: [agg (100000x128) ; x (32x256x128)] concatenated, float32.

// ---------------------------------------------------------------------------
// SpMM: side[r,:] += vals[e] * ego[cols[e],:]  (rows sorted; atomic flush on
// row change only). Block = 128 threads (one per column), 64 edges per block.
// ---------------------------------------------------------------------------
__global__ __launch_bounds__(128) void spmm_kernel(
    const float* __restrict__ ego, const float* __restrict__ vals,
    const int* __restrict__ rows, const int* __restrict__ cols,
    float* __restrict__ side, int nnz)
{
    __shared__ int s_row[64];
    __shared__ int s_col[64];
    __shared__ float s_val[64];
    int e0 = blockIdx.x * 64;
    int n = nnz - e0; if (n > 64) n = 64;
    int tid = threadIdx.x;
    if (tid < n) {
        s_row[tid] = rows[e0 + tid];
        s_col[tid] = cols[e0 + tid];
        s_val[tid] = vals[e0 + tid];
    }
    __syncthreads();
    int c = tid;                       // column 0..127
    float acc = 0.f;
    int cur = s_row[0];
    for (int e = 0; e < n; ++e) {
        int r = s_row[e];
        if (r != cur) {
            atomicAdd(&side[(size_t)cur * 128 + c], acc);
            acc = 0.f; cur = r;
        }
        acc = fmaf(s_val[e], ego[(size_t)s_col[e] * 128 + c], acc);
    }
    atomicAdd(&side[(size_t)cur * 128 + c], acc);
}

// ---------------------------------------------------------------------------
// Bi-interaction fused GEMM:
//   agg = leaky((ego+side)@W1+b1) + leaky((ego*side)@W2+b2)
// 64x64 tile, 256 threads, 4x4 microtile, K=128, N=128.
// ---------------------------------------------------------------------------
__global__ __launch_bounds__(256) void bi_gemm_kernel(
    const float* __restrict__ ego, const float* __restrict__ side,
    const float* __restrict__ W1, const float* __restrict__ b1,
    const float* __restrict__ W2, const float* __restrict__ b2,
    float* __restrict__ out, int M)
{
    __shared__ alignas(16) float UsT[32][68];   // (k, row) transposed+padded
    __shared__ alignas(16) float MsT[32][68];
    __shared__ alignas(16) float W1s[32][64];
    __shared__ alignas(16) float W2s[32][64];

    int tid = threadIdx.x;
    int tx = tid & 15, ty = tid >> 4;
    int bm = blockIdx.y * 64;
    int bn = blockIdx.x * 64;

    float acc1[4][4] = {};
    float acc2[4][4] = {};

    for (int k0 = 0; k0 < 128; k0 += 32) {
        // A tiles: 64 rows x 32 cols; one 8-elem chunk per thread
        {
            int r = tid >> 2, q = tid & 3;
            int gr = bm + r;
            float e[8], s[8];
            if (gr < M) {
                float4 ea = *(const float4*)(ego + (size_t)gr * 128 + k0 + q * 8);
                float4 eb = *(const float4*)(ego + (size_t)gr * 128 + k0 + q * 8 + 4);
                float4 sa = *(const float4*)(side + (size_t)gr * 128 + k0 + q * 8);
                float4 sb = *(const float4*)(side + (size_t)gr * 128 + k0 + q * 8 + 4);
                e[0]=ea.x; e[1]=ea.y; e[2]=ea.z; e[3]=ea.w;
                e[4]=eb.x; e[5]=eb.y; e[6]=eb.z; e[7]=eb.w;
                s[0]=sa.x; s[1]=sa.y; s[2]=sa.z; s[3]=sa.w;
                s[4]=sb.x; s[5]=sb.y; s[6]=sb.z; s[7]=sb.w;
            } else {
                #pragma unroll
                for (int j = 0; j < 8; ++j) { e[j] = 0.f; s[j] = 0.f; }
            }
            #pragma unroll
            for (int j = 0; j < 8; ++j) {
                UsT[q * 8 + j][r] = e[j] + s[j];
                MsT[q * 8 + j][r] = e[j] * s[j];
            }
        }
        // W tiles: 32 rows x 64 cols; 8 elems per thread
        {
            int r = tid >> 3, q = tid & 7;
            float4 wa = *(const float4*)(W1 + (size_t)(k0 + r) * 128 + bn + q * 8);
            float4 wb = *(const float4*)(W1 + (size_t)(k0 + r) * 128 + bn + q * 8 + 4);
            float4 va = *(const float4*)(W2 + (size_t)(k0 + r) * 128 + bn + q * 8);
            float4 vb = *(const float4*)(W2 + (size_t)(k0 + r) * 128 + bn + q * 8 + 4);
            *(float4*)&W1s[r][q * 8 + 0] = wa;
            *(float4*)&W1s[r][q * 8 + 4] = wb;
            *(float4*)&W2s[r][q * 8 + 0] = va;
            *(float4*)&W2s[r][q * 8 + 4] = vb;
        }
        __syncthreads();
        #pragma unroll
        for (int kk = 0; kk < 32; ++kk) {
            float4 u4 = *(const float4*)&UsT[kk][ty * 4];
            float4 m4 = *(const float4*)&MsT[kk][ty * 4];
            float4 a4 = *(const float4*)&W1s[kk][tx * 4];
            float4 c4 = *(const float4*)&W2s[kk][tx * 4];
            float u[4] = {u4.x, u4.y, u4.z, u4.w};
            float m[4] = {m4.x, m4.y, m4.z, m4.w};
            float wa[4] = {a4.x, a4.y, a4.z, a4.w};
            float wc[4] = {c4.x, c4.y, c4.z, c4.w};
            #pragma unroll
            for (int i = 0; i < 4; ++i) {
                #pragma unroll
                for (int j = 0; j < 4; ++j) {
                    acc1[i][j] = fmaf(u[i], wa[j], acc1[i][j]);
                    acc2[i][j] = fmaf(m[i], wc[j], acc2[i][j]);
                }
            }
        }
        __syncthreads();
    }
    #pragma unroll
    for (int i = 0; i < 4; ++i) {
        int r = bm + ty * 4 + i;
        if (r < M) {
            float4 o;
            #pragma unroll
            for (int j = 0; j < 4; ++j) {
                int c = bn + tx * 4 + j;
                float v1 = acc1[i][j] + b1[c];
                v1 = v1 > 0.f ? v1 : 0.01f * v1;
                float v2 = acc2[i][j] + b2[c];
                v2 = v2 > 0.f ? v2 : 0.01f * v2;
                ((float*)&o)[j] = v1 + v2;
            }
            *(float4*)(out + (size_t)r * 128 + bn + tx * 4) = o;
        }
    }
}

// ---------------------------------------------------------------------------
// Generic f32 GEMM: C = act(A @ W + bias [+ R]).  A (M,K), W (K,N), f32.
// M % 64 == 0, N % 64 == 0, K % 32 == 0.  act: 0 none, 1 relu.
// ---------------------------------------------------------------------------
__global__ __launch_bounds__(256) void gemm_kernel(
    const float* __restrict__ A, const float* __restrict__ W,
    const float* __restrict__ bias, const float* __restrict__ R,
    float* __restrict__ C, int M, int N, int K, int act)
{
    __shared__ alignas(16) float AsT[32][68];
    __shared__ alignas(16) float Bs[32][64];

    int tid = threadIdx.x;
    int tx = tid & 15, ty = tid >> 4;
    int bm = blockIdx.y * 64;
    int bn = blockIdx.x * 64;

    float acc[4][4] = {};

    for (int k0 = 0; k0 < K; k0 += 32) {
        #pragma unroll
        for (int i = 0; i < 2; ++i) {
            int idx = tid + i * 256;       // 0..511 float4 chunks
            int r = idx >> 3, q = idx & 7;
            float4 a4 = *(const float4*)(A + (size_t)(bm + r) * K + k0 + q * 4);
            AsT[q * 4 + 0][r] = a4.x;
            AsT[q * 4 + 1][r] = a4.y;
            AsT[q * 4 + 2][r] = a4.z;
            AsT[q * 4 + 3][r] = a4.w;
        }
        {
            int r = tid >> 3, q = tid & 7;
            float4 wa = *(const float4*)(W + (size_t)(k0 + r) * N + bn + q * 8);
            float4 wb = *(const float4*)(W + (size_t)(k0 + r) * N + bn + q * 8 + 4);
            *(float4*)&Bs[r][q * 8 + 0] = wa;
            *(float4*)&Bs[r][q * 8 + 4] = wb;
        }
        __syncthreads();
        #pragma unroll
        for (int kk = 0; kk < 32; ++kk) {
            float4 a4 = *(const float4*)&AsT[kk][ty * 4];
            float4 b4 = *(const float4*)&Bs[kk][tx * 4];
            float a[4] = {a4.x, a4.y, a4.z, a4.w};
            float b[4] = {b4.x, b4.y, b4.z, b4.w};
            #pragma unroll
            for (int i = 0; i < 4; ++i) {
                #pragma unroll
                for (int j = 0; j < 4; ++j)
                    acc[i][j] = fmaf(a[i], b[j], acc[i][j]);
            }
        }
        __syncthreads();
    }
    #pragma unroll
    for (int i = 0; i < 4; ++i) {
        int r = bm + ty * 4 + i;
        float4 o;
        float* po = C + (size_t)r * N + bn + tx * 4;
        #pragma unroll
        for (int j = 0; j < 4; ++j) {
            int c = bn + tx * 4 + j;
            float v = acc[i][j] + bias[c];
            if (R) v += R[(size_t)r * N + c];
            if (act == 1) v = fmaxf(v, 0.f);
            ((float*)&o)[j] = v;
        }
        *(float4*)po = o;
    }
}

// ---------------------------------------------------------------------------
// Attention: per block = one (batch, head). K/V staged in LDS, one thread per
// query, online softmax (no score materialization). L == 256, DK == 16.
// ---------------------------------------------------------------------------
__global__ __launch_bounds__(256) void attn_kernel(
    const float* __restrict__ q, const float* __restrict__ k,
    const float* __restrict__ v, float* __restrict__ o, int NH)
{
    const int L = 256, DK = 16;
    __shared__ float Ks[L * DK];
    __shared__ float Vs[L * DK];
    int b = blockIdx.x / NH, h = blockIdx.x % NH;
    int tid = threadIdx.x;

    for (int i = tid; i < L * DK; i += 256) {
        int l = i >> 4, d = i & 15;
        size_t g = ((size_t)(b * L + l) * NH + h) * DK + d;
        Ks[i] = k[g];
        Vs[i] = v[g];
    }
    __syncthreads();

    int l = tid;
    size_t qbase = ((size_t)(b * L + l) * NH + h) * DK;
    float qr[16];
    #pragma unroll
    for (int d = 0; d < 16; ++d) qr[d] = q[qbase + d];

    float mmax = -1e30f, ssum = 0.f;
    for (int kk = 0; kk < L; ++kk) {
        float dot = 0.f;
        #pragma unroll
        for (int d = 0; d < 16; ++d) dot = fmaf(qr[d], Ks[kk * 16 + d], dot);
        dot *= 0.25f;                       // 1/sqrt(16)
        float nm = fmaxf(mmax, dot);
        ssum = ssum * __expf(mmax - nm) + __expf(dot - nm);
        mmax = nm;
    }
    float inv = 1.f / ssum;
    float acc[16];
    #pragma unroll
    for (int d = 0; d < 16; ++d) acc[d] = 0.f;
    for (int kk = 0; kk < L; ++kk) {
        float dot = 0.f;
        #pragma unroll
        for (int d = 0; d < 16; ++d) dot = fmaf(qr[d], Ks[kk * 16 + d], dot);
        float p = __expf(dot * 0.25f - mmax) * inv;
        #pragma unroll
        for (int d = 0; d < 16; ++d) acc[d] = fmaf(p, Vs[kk * 16 + d], acc[d]);
    }
    #pragma unroll
    for (int d = 0; d < 16; ++d) o[qbase + d] = acc[d];
}

// ---------------------------------------------------------------------------
// LayerNorm over rows of 128. One wave per row (2 elems/lane).
// ---------------------------------------------------------------------------
__global__ __launch_bounds__(256) void ln_kernel(
    const float* __restrict__ X, const float* __restrict__ g,
    const float* __restrict__ b, float* __restrict__ outF, int Mrows)
{
    int wave = threadIdx.x >> 6;
    int lane = threadIdx.x & 63;
    int r = blockIdx.x * 4 + wave;
    if (r >= Mrows) return;

    float2 x2 = *(const float2*)(X + (size_t)r * 128 + lane * 2);
    float s = x2.x + x2.y;
    float ss = x2.x * x2.x + x2.y * x2.y;
    #pragma unroll
    for (int off = 32; off > 0; off >>= 1) {
        s  += __shfl_xor(s, off, 64);
        ss += __shfl_xor(ss, off, 64);
    }
    float mean = s * (1.f / 128.f);
    float var = ss * (1.f / 128.f) - mean * mean;
    float rstd = rsqrtf(var + 1e-5f);
    float y0 = (x2.x - mean) * rstd * g[lane * 2 + 0] + b[lane * 2 + 0];
    float y1 = (x2.y - mean) * rstd * g[lane * 2 + 1] + b[lane * 2 + 1];
    *(float2*)(outF + (size_t)r * 128 + lane * 2) = make_float2(y0, y1);
}

extern "C" void kernel_launch(void* const* d_in, const int* in_sizes, int n_in,
                              void* d_out, int out_size, void* d_ws, size_t ws_size,
                              hipStream_t stream) {
    const float* ego    = (const float*)d_in[0];
    const float* vals   = (const float*)d_in[1];
    const float* W1     = (const float*)d_in[2];
    const float* b1     = (const float*)d_in[3];
    const float* W2     = (const float*)d_in[4];
    const float* b2     = (const float*)d_in[5];
    const float* enc_in = (const float*)d_in[6];
    const float* wq  = (const float*)d_in[7];
    const float* bq  = (const float*)d_in[8];
    const float* wk  = (const float*)d_in[9];
    const float* bk  = (const float*)d_in[10];
    const float* wv  = (const float*)d_in[11];
    const float* bv  = (const float*)d_in[12];
    const float* wo  = (const float*)d_in[13];
    const float* bo  = (const float*)d_in[14];
    const float* ln1_g = (const float*)d_in[15];
    const float* ln1_b = (const float*)d_in[16];
    const float* cw1 = (const float*)d_in[17];
    const float* cb1 = (const float*)d_in[18];
    const float* cw2 = (const float*)d_in[19];
    const float* cb2 = (const float*)d_in[20];
    const float* ln2_g = (const float*)d_in[21];
    const float* ln2_b = (const float*)d_in[22];
    const int* rows = (const int*)d_in[23];
    const int* cols = (const int*)d_in[24];

    const int D = 128, DI = 512, NH = 8, L = 256;
    const int Nn   = in_sizes[0] / D;        // 100000
    const int nnz  = in_sizes[1];            // 2000000
    const int NL   = in_sizes[7] / (D * D);  // 2
    const int Menc = in_sizes[6] / D;        // 8192 (= B*L)
    const int Bb   = Menc / L;               // 32

    float* ws = (float*)d_ws;
    size_t off = 0;
    float* side = ws + off; off += (size_t)Nn * D;
    float* Qb = ws + off; off += (size_t)Menc * D;
    float* Kb = ws + off; off += (size_t)Menc * D;
    float* Vb = ws + off; off += (size_t)Menc * D;
    float* Ob = ws + off; off += (size_t)Menc * D;
    float* Tb = ws + off; off += (size_t)Menc * D;
    float* XA = ws + off; off += (size_t)Menc * D;
    float* XB = ws + off; off += (size_t)Menc * D;
    float* Hb = ws + off; off += (size_t)Menc * DI;

    float* outAgg = (float*)d_out;
    float* outX   = (float*)d_out + (size_t)Nn * D;

    // ---- Part A: SpMM + bi-interaction ----
    hipMemsetAsync(side, 0, (size_t)Nn * D * sizeof(float), stream);
    spmm_kernel<<<(nnz + 63) / 64, 128, 0, stream>>>(ego, vals, rows, cols, side, nnz);
    bi_gemm_kernel<<<dim3(D / 64, (Nn + 63) / 64), 256, 0, stream>>>(
        ego, side, W1, b1, W2, b2, outAgg, Nn);

    // ---- Part B: transformer encoder ----
    const float* x = enc_in;
    for (int i = 0; i < NL; ++i) {
        const size_t wOff = (size_t)i * D * D;
        gemm_kernel<<<dim3(D / 64, Menc / 64), 256, 0, stream>>>(
            x, wq + wOff, bq + (size_t)i * D, nullptr, Qb, Menc, D, D, 0);
        gemm_kernel<<<dim3(D / 64, Menc / 64), 256, 0, stream>>>(
            x, wk + wOff, bk + (size_t)i * D, nullptr, Kb, Menc, D, D, 0);
        gemm_kernel<<<dim3(D / 64, Menc / 64), 256, 0, stream>>>(
            x, wv + wOff, bv + (size_t)i * D, nullptr, Vb, Menc, D, D, 0);
        attn_kernel<<<Bb * NH, 256, 0, stream>>>(Qb, Kb, Vb, Ob, NH);
        gemm_kernel<<<dim3(D / 64, Menc / 64), 256, 0, stream>>>(
            Ob, wo + wOff, bo + (size_t)i * D, x, Tb, Menc, D, D, 0);
        ln_kernel<<<Menc / 4, 256, 0, stream>>>(
            Tb, ln1_g + (size_t)i * D, ln1_b + (size_t)i * D, XA, Menc);
        gemm_kernel<<<dim3(DI / 64, Menc / 64), 256, 0, stream>>>(
            XA, cw1 + (size_t)i * D * DI, cb1 + (size_t)i * DI, nullptr, Hb, Menc, DI, D, 1);
        gemm_kernel<<<dim3(D / 64, Menc / 64), 256, 0, stream>>>(
            Hb, cw2 + (size_t)i * DI * D, cb2 + (size_t)i * D, XA, Tb, Menc, D, DI, 0);
        if (i == NL - 1) {
            ln_kernel<<<Menc / 4, 256, 0, stream>>>(
                Tb, ln2_g + (size_t)i * D, ln2_b + (size_t)i * D, outX, Menc);
        } else {
            ln_kernel<<<Menc / 4, 256, 0, stream>>>(
                Tb, ln2_g + (size_t)i * D, ln2_b + (size_t)i * D, XB, Menc);
            x = XB;
        }
    }
}

// Round 3
// 646.475 us; speedup vs baseline: 1.1882x; 1.1882x over previous
//
#include <hip/hip_runtime.h>

typedef __attribute__((ext_vector_type(8))) short bf16x8;
typedef __attribute__((ext_vector_type(4))) float f32x4;

__device__ __forceinline__ unsigned short f2b(float f) {
    union { float f; unsigned int i; } u; u.f = f;
    return (unsigned short)((u.i + 0x7FFFu + ((u.i >> 16) & 1u)) >> 16);
}
__device__ __forceinline__ unsigned int packbf2(float a, float b) {
    return (unsigned int)f2b(a) | ((unsigned int)f2b(b) << 16);
}

// ---------------------------------------------------------------------------
// SpMM: side[r,:] += vals[e] * ego[cols[e],:]  (rows sorted). Block = 256
// threads = 4 waves; each wave owns 64 edges; lane holds 2 columns (float2).
// Depth-8 register prefetch queue (fully unrolled inner loop keeps it in
// VGPRs) to raise memory-level parallelism.
// ---------------------------------------------------------------------------
__global__ __launch_bounds__(256) void spmm_kernel(
    const float* __restrict__ ego, const float* __restrict__ vals,
    const int* __restrict__ rows, const int* __restrict__ cols,
    float* __restrict__ side, int nnz)
{
    __shared__ int s_row[256];
    __shared__ int s_col[256];
    __shared__ float s_val[256];
    int e0 = blockIdx.x * 256;
    int n = nnz - e0; if (n > 256) n = 256;
    int tid = threadIdx.x;
    if (tid < n) {
        s_row[tid] = rows[e0 + tid];
        s_col[tid] = cols[e0 + tid];
        s_val[tid] = vals[e0 + tid];
    }
    __syncthreads();

    int wave = tid >> 6, lane = tid & 63;
    int base = wave * 64;
    int cnt = n - base; if (cnt > 64) cnt = 64;
    if (cnt <= 0) return;
    int c2 = lane * 2;

    float2 pre[8];
    #pragma unroll
    for (int j = 0; j < 8; ++j) {
        pre[j] = (j < cnt) ? *(const float2*)(ego + (size_t)s_col[base + j] * 128 + c2)
                           : make_float2(0.f, 0.f);
    }
    float ax = 0.f, ay = 0.f;
    int cur = s_row[base];
    for (int eo = 0; eo < 64; eo += 8) {
        if (eo >= cnt) break;
        #pragma unroll
        for (int j = 0; j < 8; ++j) {
            int e = eo + j;
            if (e < cnt) {
                int r = s_row[base + e];
                float vv = s_val[base + e];
                float2 p = pre[j];
                int nx = e + 8;
                if (nx < cnt)
                    pre[j] = *(const float2*)(ego + (size_t)s_col[base + nx] * 128 + c2);
                if (r != cur) {
                    atomicAdd(&side[(size_t)cur * 128 + c2], ax);
                    atomicAdd(&side[(size_t)cur * 128 + c2 + 1], ay);
                    ax = 0.f; ay = 0.f; cur = r;
                }
                ax = fmaf(vv, p.x, ax);
                ay = fmaf(vv, p.y, ay);
            }
        }
    }
    atomicAdd(&side[(size_t)cur * 128 + c2], ax);
    atomicAdd(&side[(size_t)cur * 128 + c2 + 1], ay);
}

// ---------------------------------------------------------------------------
// MFMA GEMM core: C[bm:bm+128, bn:bn+64] = act(A@W + bias [+R]).
// A f32 (M,K) row-major, W f32 (K,N) row-major, staged to LDS as bf16.
// 256 threads = 4 waves stacked in m (32 rows each), 16x16x32 bf16 MFMA.
// A-frag: A[m=lane&15][k=quad*8+j]; B-frag: B[k=quad*8+j][n=lane&15];
// C/D: col=lane&15, row=quad*4+reg.
// ---------------------------------------------------------------------------
#define LDAB 40   // bf16 row stride in LDS (pad: 80B rows -> 2-way conflicts only)

__device__ __forceinline__ void gemm_core(
    const float* __restrict__ A, const float* __restrict__ W,
    const float* __restrict__ bias, const float* __restrict__ R,
    float* __restrict__ C, int M, int N, int K, int act,
    int bm, int bn, unsigned short* As, unsigned short* Bs)
{
    int tid = threadIdx.x, wave = tid >> 6, lane = tid & 63;
    int lm = lane & 15, quad = lane >> 4;

    f32x4 acc[2][4];
    #pragma unroll
    for (int i = 0; i < 2; ++i)
        #pragma unroll
        for (int j = 0; j < 4; ++j) acc[i][j] = (f32x4)(0.f);

    for (int k0 = 0; k0 < K; k0 += 32) {
        // stage A tile: 128 rows x 32 k (bf16), 512 8-elem items
        #pragma unroll
        for (int it = 0; it < 2; ++it) {
            int i = tid + it * 256;
            int m = i >> 2, kc = (i & 3) * 8;
            int gm = bm + m;
            float4 a0, a1;
            if (gm < M) {
                const float* p = A + (size_t)gm * K + k0 + kc;
                a0 = *(const float4*)p; a1 = *(const float4*)(p + 4);
            } else { a0 = make_float4(0,0,0,0); a1 = a0; }
            uint4 pk;
            pk.x = packbf2(a0.x, a0.y); pk.y = packbf2(a0.z, a0.w);
            pk.z = packbf2(a1.x, a1.y); pk.w = packbf2(a1.z, a1.w);
            *(uint4*)&As[m * LDAB + kc] = pk;
        }
        // stage B tile transposed: Bs[n][k], 64 n x 32 k
        {
            int nn = tid & 63, kq = (tid >> 6) * 8;
            const float* p = W + (size_t)(k0 + kq) * N + bn + nn;
            float w[8];
            #pragma unroll
            for (int j = 0; j < 8; ++j) w[j] = p[(size_t)j * N];
            uint4 pk;
            pk.x = packbf2(w[0], w[1]); pk.y = packbf2(w[2], w[3]);
            pk.z = packbf2(w[4], w[5]); pk.w = packbf2(w[6], w[7]);
            *(uint4*)&Bs[nn * LDAB + kq] = pk;
        }
        __syncthreads();
        bf16x8 af[2], bfr[4];
        #pragma unroll
        for (int mi = 0; mi < 2; ++mi)
            af[mi] = *(bf16x8*)&As[(wave * 32 + mi * 16 + lm) * LDAB + quad * 8];
        #pragma unroll
        for (int ni = 0; ni < 4; ++ni)
            bfr[ni] = *(bf16x8*)&Bs[(ni * 16 + lm) * LDAB + quad * 8];
        #pragma unroll
        for (int mi = 0; mi < 2; ++mi)
            #pragma unroll
            for (int ni = 0; ni < 4; ++ni)
                acc[mi][ni] = __builtin_amdgcn_mfma_f32_16x16x32_bf16(
                    af[mi], bfr[ni], acc[mi][ni], 0, 0, 0);
        __syncthreads();
    }
    #pragma unroll
    for (int mi = 0; mi < 2; ++mi) {
        #pragma unroll
        for (int r = 0; r < 4; ++r) {
            int row = bm + wave * 32 + mi * 16 + quad * 4 + r;
            if (row < M) {
                #pragma unroll
                for (int ni = 0; ni < 4; ++ni) {
                    int col = bn + ni * 16 + lm;
                    float v = acc[mi][ni][r] + bias[col];
                    if (R) v += R[(size_t)row * N + col];
                    if (act) v = fmaxf(v, 0.f);
                    C[(size_t)row * N + col] = v;
                }
            }
        }
    }
}

__global__ __launch_bounds__(256) void gemm_mfma(
    const float* __restrict__ A, const float* __restrict__ W,
    const float* __restrict__ bias, const float* __restrict__ R,
    float* __restrict__ C, int M, int N, int K, int act)
{
    __shared__ unsigned short As[128 * LDAB];
    __shared__ unsigned short Bs[64 * LDAB];
    gemm_core(A, W, bias, R, C, M, N, K, act,
              blockIdx.y * 128, blockIdx.x * 64, As, Bs);
}

// fused Q/K/V projection: grid.x = 6 (3 outputs x 2 n-halves)
__global__ __launch_bounds__(256) void qkv_mfma(
    const float* __restrict__ A,
    const float* __restrict__ wq, const float* __restrict__ wk, const float* __restrict__ wv,
    const float* __restrict__ bq, const float* __restrict__ bk, const float* __restrict__ bv,
    float* __restrict__ Q, float* __restrict__ Ko, float* __restrict__ V, int M, int D)
{
    __shared__ unsigned short As[128 * LDAB];
    __shared__ unsigned short Bs[64 * LDAB];
    int sel = blockIdx.x >> 1;
    const float* W = (sel == 0) ? wq : (sel == 1) ? wk : wv;
    const float* b = (sel == 0) ? bq : (sel == 1) ? bk : bv;
    float* C = (sel == 0) ? Q : (sel == 1) ? Ko : V;
    gemm_core(A, W, b, nullptr, C, M, D, D, 0,
              blockIdx.y * 128, (blockIdx.x & 1) * 64, As, Bs);
}

// ---------------------------------------------------------------------------
// Bi-interaction fused MFMA GEMM:
//   agg = leaky((ego+side)@W1+b1) + leaky((ego*side)@W2+b2), K=N=128
// ---------------------------------------------------------------------------
__global__ __launch_bounds__(256) void bi_gemm_mfma(
    const float* __restrict__ ego, const float* __restrict__ side,
    const float* __restrict__ W1, const float* __restrict__ b1,
    const float* __restrict__ W2, const float* __restrict__ b2,
    float* __restrict__ out, int M)
{
    __shared__ unsigned short Us[128 * LDAB];
    __shared__ unsigned short Ms[128 * LDAB];
    __shared__ unsigned short W1s[64 * LDAB];
    __shared__ unsigned short W2s[64 * LDAB];

    int tid = threadIdx.x, wave = tid >> 6, lane = tid & 63;
    int lm = lane & 15, quad = lane >> 4;
    int bm = blockIdx.y * 128, bn = blockIdx.x * 64;

    f32x4 acc1[2][4], acc2[2][4];
    #pragma unroll
    for (int i = 0; i < 2; ++i)
        #pragma unroll
        for (int j = 0; j < 4; ++j) { acc1[i][j] = (f32x4)(0.f); acc2[i][j] = (f32x4)(0.f); }

    for (int k0 = 0; k0 < 128; k0 += 32) {
        #pragma unroll
        for (int it = 0; it < 2; ++it) {
            int i = tid + it * 256;
            int m = i >> 2, kc = (i & 3) * 8;
            int gm = bm + m;
            float e[8], s[8];
            if (gm < M) {
                const float* pe = ego + (size_t)gm * 128 + k0 + kc;
                const float* ps = side + (size_t)gm * 128 + k0 + kc;
                float4 e0 = *(const float4*)pe, e1 = *(const float4*)(pe + 4);
                float4 s0 = *(const float4*)ps, s1 = *(const float4*)(ps + 4);
                e[0]=e0.x; e[1]=e0.y; e[2]=e0.z; e[3]=e0.w;
                e[4]=e1.x; e[5]=e1.y; e[6]=e1.z; e[7]=e1.w;
                s[0]=s0.x; s[1]=s0.y; s[2]=s0.z; s[3]=s0.w;
                s[4]=s1.x; s[5]=s1.y; s[6]=s1.z; s[7]=s1.w;
            } else {
                #pragma unroll
                for (int j = 0; j < 8; ++j) { e[j] = 0.f; s[j] = 0.f; }
            }
            uint4 pu, pm;
            pu.x = packbf2(e[0]+s[0], e[1]+s[1]); pu.y = packbf2(e[2]+s[2], e[3]+s[3]);
            pu.z = packbf2(e[4]+s[4], e[5]+s[5]); pu.w = packbf2(e[6]+s[6], e[7]+s[7]);
            pm.x = packbf2(e[0]*s[0], e[1]*s[1]); pm.y = packbf2(e[2]*s[2], e[3]*s[3]);
            pm.z = packbf2(e[4]*s[4], e[5]*s[5]); pm.w = packbf2(e[6]*s[6], e[7]*s[7]);
            *(uint4*)&Us[m * LDAB + kc] = pu;
            *(uint4*)&Ms[m * LDAB + kc] = pm;
        }
        {
            int nn = tid & 63, kq = (tid >> 6) * 8;
            const float* p1 = W1 + (size_t)(k0 + kq) * 128 + bn + nn;
            const float* p2 = W2 + (size_t)(k0 + kq) * 128 + bn + nn;
            float wa[8], wb[8];
            #pragma unroll
            for (int j = 0; j < 8; ++j) { wa[j] = p1[(size_t)j * 128]; wb[j] = p2[(size_t)j * 128]; }
            uint4 pk1, pk2;
            pk1.x = packbf2(wa[0],wa[1]); pk1.y = packbf2(wa[2],wa[3]);
            pk1.z = packbf2(wa[4],wa[5]); pk1.w = packbf2(wa[6],wa[7]);
            pk2.x = packbf2(wb[0],wb[1]); pk2.y = packbf2(wb[2],wb[3]);
            pk2.z = packbf2(wb[4],wb[5]); pk2.w = packbf2(wb[6],wb[7]);
            *(uint4*)&W1s[nn * LDAB + kq] = pk1;
            *(uint4*)&W2s[nn * LDAB + kq] = pk2;
        }
        __syncthreads();
        bf16x8 au[2], am[2], bf1[4], bf2[4];
        #pragma unroll
        for (int mi = 0; mi < 2; ++mi) {
            au[mi] = *(bf16x8*)&Us[(wave * 32 + mi * 16 + lm) * LDAB + quad * 8];
            am[mi] = *(bf16x8*)&Ms[(wave * 32 + mi * 16 + lm) * LDAB + quad * 8];
        }
        #pragma unroll
        for (int ni = 0; ni < 4; ++ni) {
            bf1[ni] = *(bf16x8*)&W1s[(ni * 16 + lm) * LDAB + quad * 8];
            bf2[ni] = *(bf16x8*)&W2s[(ni * 16 + lm) * LDAB + quad * 8];
        }
        #pragma unroll
        for (int mi = 0; mi < 2; ++mi)
            #pragma unroll
            for (int ni = 0; ni < 4; ++ni) {
                acc1[mi][ni] = __builtin_amdgcn_mfma_f32_16x16x32_bf16(
                    au[mi], bf1[ni], acc1[mi][ni], 0, 0, 0);
                acc2[mi][ni] = __builtin_amdgcn_mfma_f32_16x16x32_bf16(
                    am[mi], bf2[ni], acc2[mi][ni], 0, 0, 0);
            }
        __syncthreads();
    }
    #pragma unroll
    for (int mi = 0; mi < 2; ++mi) {
        #pragma unroll
        for (int r = 0; r < 4; ++r) {
            int row = bm + wave * 32 + mi * 16 + quad * 4 + r;
            if (row < M) {
                #pragma unroll
                for (int ni = 0; ni < 4; ++ni) {
                    int col = bn + ni * 16 + lm;
                    float v1 = acc1[mi][ni][r] + b1[col];
                    v1 = v1 > 0.f ? v1 : 0.01f * v1;
                    float v2 = acc2[mi][ni][r] + b2[col];
                    v2 = v2 > 0.f ? v2 : 0.01f * v2;
                    out[(size_t)row * 128 + col] = v1 + v2;
                }
            }
        }
    }
}

// ---------------------------------------------------------------------------
// Attention: block = (b, h, half of queries), 128 threads, single-pass
// online softmax. L == 256, DK == 16.
// ---------------------------------------------------------------------------
__global__ __launch_bounds__(128) void attn_kernel(
    const float* __restrict__ q, const float* __restrict__ k,
    const float* __restrict__ v, float* __restrict__ o, int NH)
{
    const int L = 256, DK = 16;
    __shared__ float Ks[L * DK];
    __shared__ float Vs[L * DK];
    int bh = blockIdx.x >> 1;
    int half = blockIdx.x & 1;
    int b = bh / NH, h = bh % NH;
    int tid = threadIdx.x;

    for (int i = tid; i < L * 4; i += 128) {
        int l = i >> 2, d4 = (i & 3) * 4;
        size_t g = ((size_t)(b * L + l) * NH + h) * DK + d4;
        *(float4*)&Ks[l * 16 + d4] = *(const float4*)(k + g);
        *(float4*)&Vs[l * 16 + d4] = *(const float4*)(v + g);
    }
    __syncthreads();

    int l = half * 128 + tid;
    size_t qbase = ((size_t)(b * L + l) * NH + h) * DK;
    float qr[16];
    #pragma unroll
    for (int d4 = 0; d4 < 4; ++d4) {
        float4 t = *(const float4*)(q + qbase + d4 * 4);
        qr[d4*4+0] = t.x * 0.25f; qr[d4*4+1] = t.y * 0.25f;
        qr[d4*4+2] = t.z * 0.25f; qr[d4*4+3] = t.w * 0.25f;
    }
    float acc[16];
    #pragma unroll
    for (int d = 0; d < 16; ++d) acc[d] = 0.f;
    float mmax = -1e30f, ssum = 0.f;
    for (int kk = 0; kk < L; ++kk) {
        float dot = 0.f;
        #pragma unroll
        for (int d4 = 0; d4 < 4; ++d4) {
            float4 kv = *(const float4*)&Ks[kk * 16 + d4 * 4];
            dot = fmaf(qr[d4*4+0], kv.x, dot);
            dot = fmaf(qr[d4*4+1], kv.y, dot);
            dot = fmaf(qr[d4*4+2], kv.z, dot);
            dot = fmaf(qr[d4*4+3], kv.w, dot);
        }
        if (dot > mmax) {
            float alpha = __expf(mmax - dot);
            ssum *= alpha;
            #pragma unroll
            for (int d = 0; d < 16; ++d) acc[d] *= alpha;
            mmax = dot;
        }
        float p = __expf(dot - mmax);
        ssum += p;
        #pragma unroll
        for (int d4 = 0; d4 < 4; ++d4) {
            float4 vv = *(const float4*)&Vs[kk * 16 + d4 * 4];
            acc[d4*4+0] = fmaf(p, vv.x, acc[d4*4+0]);
            acc[d4*4+1] = fmaf(p, vv.y, acc[d4*4+1]);
            acc[d4*4+2] = fmaf(p, vv.z, acc[d4*4+2]);
            acc[d4*4+3] = fmaf(p, vv.w, acc[d4*4+3]);
        }
    }
    float inv = 1.f / ssum;
    #pragma unroll
    for (int d4 = 0; d4 < 4; ++d4) {
        float4 t;
        t.x = acc[d4*4+0] * inv; t.y = acc[d4*4+1] * inv;
        t.z = acc[d4*4+2] * inv; t.w = acc[d4*4+3] * inv;
        *(float4*)(o + qbase + d4 * 4) = t;
    }
}

// ---------------------------------------------------------------------------
// LayerNorm over rows of 128. One wave per row (2 elems/lane).
// ---------------------------------------------------------------------------
__global__ __launch_bounds__(256) void ln_kernel(
    const float* __restrict__ X, const float* __restrict__ g,
    const float* __restrict__ b, float* __restrict__ outF, int Mrows)
{
    int wave = threadIdx.x >> 6;
    int lane = threadIdx.x & 63;
    int r = blockIdx.x * 4 + wave;
    if (r >= Mrows) return;

    float2 x2 = *(const float2*)(X + (size_t)r * 128 + lane * 2);
    float s = x2.x + x2.y;
    float ss = x2.x * x2.x + x2.y * x2.y;
    #pragma unroll
    for (int off = 32; off > 0; off >>= 1) {
        s  += __shfl_xor(s, off, 64);
        ss += __shfl_xor(ss, off, 64);
    }
    float mean = s * (1.f / 128.f);
    float var = ss * (1.f / 128.f) - mean * mean;
    float rstd = rsqrtf(var + 1e-5f);
    float y0 = (x2.x - mean) * rstd * g[lane * 2 + 0] + b[lane * 2 + 0];
    float y1 = (x2.y - mean) * rstd * g[lane * 2 + 1] + b[lane * 2 + 1];
    *(float2*)(outF + (size_t)r * 128 + lane * 2) = make_float2(y0, y1);
}

extern "C" void kernel_launch(void* const* d_in, const int* in_sizes, int n_in,
                              void* d_out, int out_size, void* d_ws, size_t ws_size,
                              hipStream_t stream) {
    const float* ego    = (const float*)d_in[0];
    const float* vals   = (const float*)d_in[1];
    const float* W1     = (const float*)d_in[2];
    const float* b1     = (const float*)d_in[3];
    const float* W2     = (const float*)d_in[4];
    const float* b2     = (const float*)d_in[5];
    const float* enc_in = (const float*)d_in[6];
    const float* wq  = (const float*)d_in[7];
    const float* bq  = (const float*)d_in[8];
    const float* wk  = (const float*)d_in[9];
    const float* bk  = (const float*)d_in[10];
    const float* wv  = (const float*)d_in[11];
    const float* bv  = (const float*)d_in[12];
    const float* wo  = (const float*)d_in[13];
    const float* bo  = (const float*)d_in[14];
    const float* ln1_g = (const float*)d_in[15];
    const float* ln1_b = (const float*)d_in[16];
    const float* cw1 = (const float*)d_in[17];
    const float* cb1 = (const float*)d_in[18];
    const float* cw2 = (const float*)d_in[19];
    const float* cb2 = (const float*)d_in[20];
    const float* ln2_g = (const float*)d_in[21];
    const float* ln2_b = (const float*)d_in[22];
    const int* rows = (const int*)d_in[23];
    const int* cols = (const int*)d_in[24];

    const int D = 128, DI = 512, NH = 8, L = 256;
    const int Nn   = in_sizes[0] / D;        // 100000
    const int nnz  = in_sizes[1];            // 2000000
    const int NL   = in_sizes[7] / (D * D);  // 2
    const int Menc = in_sizes[6] / D;        // 8192 (= B*L)
    const int Bb   = Menc / L;               // 32

    float* ws = (float*)d_ws;
    size_t off = 0;
    float* side = ws + off; off += (size_t)Nn * D;
    float* Qb = ws + off; off += (size_t)Menc * D;
    float* Kb = ws + off; off += (size_t)Menc * D;
    float* Vb = ws + off; off += (size_t)Menc * D;
    float* Ob = ws + off; off += (size_t)Menc * D;
    float* Tb = ws + off; off += (size_t)Menc * D;
    float* XA = ws + off; off += (size_t)Menc * D;
    float* XB = ws + off; off += (size_t)Menc * D;
    float* Hb = ws + off; off += (size_t)Menc * DI;

    float* outAgg = (float*)d_out;
    float* outX   = (float*)d_out + (size_t)Nn * D;

    // ---- Part A: SpMM + bi-interaction ----
    hipMemsetAsync(side, 0, (size_t)Nn * D * sizeof(float), stream);
    spmm_kernel<<<(nnz + 255) / 256, 256, 0, stream>>>(ego, vals, rows, cols, side, nnz);
    bi_gemm_mfma<<<dim3(2, (Nn + 127) / 128), 256, 0, stream>>>(
        ego, side, W1, b1, W2, b2, outAgg, Nn);

    // ---- Part B: transformer encoder ----
    const float* x = enc_in;
    for (int i = 0; i < NL; ++i) {
        const size_t wOff = (size_t)i * D * D;
        qkv_mfma<<<dim3(6, Menc / 128), 256, 0, stream>>>(
            x, wq + wOff, wk + wOff, wv + wOff,
            bq + (size_t)i * D, bk + (size_t)i * D, bv + (size_t)i * D,
            Qb, Kb, Vb, Menc, D);
        attn_kernel<<<Bb * NH * 2, 128, 0, stream>>>(Qb, Kb, Vb, Ob, NH);
        gemm_mfma<<<dim3(2, Menc / 128), 256, 0, stream>>>(
            Ob, wo + wOff, bo + (size_t)i * D, x, Tb, Menc, D, D, 0);
        ln_kernel<<<Menc / 4, 256, 0, stream>>>(
            Tb, ln1_g + (size_t)i * D, ln1_b + (size_t)i * D, XA, Menc);
        gemm_mfma<<<dim3(DI / 64, Menc / 128), 256, 0, stream>>>(
            XA, cw1 + (size_t)i * D * DI, cb1 + (size_t)i * DI, nullptr, Hb, Menc, DI, D, 1);
        gemm_mfma<<<dim3(2, Menc / 128), 256, 0, stream>>>(
            Hb, cw2 + (size_t)i * DI * D, cb2 + (size_t)i * D, XA, Tb, Menc, D, DI, 0);
        if (i == NL - 1) {
            ln_kernel<<<Menc / 4, 256, 0, stream>>>(
                Tb, ln2_g + (size_t)i * D, ln2_b + (size_t)i * D, outX, Menc);
        } else {
            ln_kernel<<<Menc / 4, 256, 0, stream>>>(
                Tb, ln2_g + (size_t)i * D, ln2_b + (size_t)i * D, XB, Menc);
            x = XB;
        }
    }
}